// Round 10
// baseline (224.229 us; speedup 1.0000x reference)
//
#include <hip/hip_runtime.h>
#include <hip/hip_bf16.h>

typedef __attribute__((ext_vector_type(8))) short short8;
typedef __attribute__((ext_vector_type(4))) float f32x4;
typedef __attribute__((ext_vector_type(4))) int   i32x4;

#define NTOP 1000
#define KC   256
#define MROWS 40000
#define MBLK  64

static __device__ __forceinline__ unsigned short f2bf(float x) {
    union { float f; unsigned u; } v; v.f = x;
    unsigned r = (v.u + 0x7FFFu + ((v.u >> 16) & 1u)) >> 16;
    return (unsigned short)r;
}

// Kernel 1: colsum[j] += sum over an 8-row slab of nw. colsum pre-zeroed by memset.
__global__ void k_prep(const float* __restrict__ nw,
                       float* __restrict__ colsum) {
    int j  = blockIdx.x * 256 + threadIdx.x;
    int i0 = blockIdx.y * 8;
    if (j < NTOP) {
        float s = 0.f;
        int iend = min(i0 + 8, NTOP);
        for (int i = i0; i < iend; ++i) s += nw[(size_t)i * NTOP + j];
        atomicAdd(colsum + j, s);
    }
}

// Kernel 2: build B' in MFMA-fragment order:
//   B'[((nt*8 + s)*64 + lane)] (short8) = V_j[n = nt*16 + (lane&15),
//                                             k = s*32 + (lane>>4)*8 + j]
__global__ void k_vj(const float* __restrict__ V,
                     const float* __restrict__ noise,
                     const float* __restrict__ colsum,
                     unsigned short* __restrict__ Bp) {
    int t  = blockIdx.x * 256 + threadIdx.x;   // 0 .. 64*8*64-1 = 32767
    int nt = t >> 9;
    int s  = (t >> 6) & 7;
    int l  = t & 63;
    int lm = l & 15, lq = l >> 4;
    int n  = nt * 16 + lm;
    int k0 = s * 32 + lq * 8;
    union { short8 v; unsigned short us[8]; } pk;
    if (n < NTOP) {
        float cs = colsum[n];
        #pragma unroll
        for (int j = 0; j < 8; ++j) {
            int idx = n * KC + k0 + j;
            pk.us[j] = f2bf(V[idx] * cs + 0.1f * noise[idx]);
        }
    } else {
        #pragma unroll
        for (int j = 0; j < 8; ++j) pk.us[j] = 0;
    }
    reinterpret_cast<short8*>(Bp)[t] = pk.v;
}

// Kernel 3: round-8 structure (MBLK=64, 4x B-reuse per Bf load, acc[4],
// low-pressure) but 512 THREADS = 8 waves/block, each wave sweeping 8 n-tiles.
// Same traffic as round 8 (Bf loads/block identical, A-build once/block),
// purely 2x resident waves: fixes round-8's grid-limited 2.44 waves/SIMD.
// (Round-9 lesson: do NOT shrink MBLK — Bf line-requests are the scarce
// resource; 32-row blocks doubled them and regressed.)
__global__ __launch_bounds__(512, 4) void k_main(
    const float* __restrict__ U, const float* __restrict__ w5,
    const float* __restrict__ b1, const short8* __restrict__ Bf,
    const float* __restrict__ R, const int* __restrict__ C,
    float* __restrict__ out)
{
    __shared__ short8 Afrag[4][8][64];   // [mt][s][ll] : 32 KB
    __shared__ float  rawU[5120];        // 4 U-rows    : 20 KB

    const int tid  = threadIdx.x;
    const int wave = tid >> 6;
    const int l    = tid & 63;
    const int lm = l & 15;       // output m within 16-tile (col = lane&15)
    const int lq = l >> 4;       // quad: n-subblock of 4 (row = lq*4 + r)
    const int m0 = blockIdx.x * MBLK;

    const float w0 = w5[0], w1 = w5[1], w2 = w5[2], w3 = w5[3], w4 = w5[4];
    const float bb = b1[0];

    // ---- A-build: 16 groups of 4 rows. Stage coalesced, compute from LDS. ----
    const float* ub = U + (size_t)m0 * (KC * 5);
    for (int g = 0; g < 16; ++g) {
        const float* src = ub + (size_t)g * 5120;
        {
            int idx = tid * 4;                       // 0..2047
            *reinterpret_cast<f32x4*>(&rawU[idx]) =
                *reinterpret_cast<const f32x4*>(src + idx);
            idx += 2048;                             // 2048..4095
            *reinterpret_cast<f32x4*>(&rawU[idx]) =
                *reinterpret_cast<const f32x4*>(src + idx);
            if (tid < 256) {                         // 4096..5119
                idx = 4096 + tid * 4;
                *reinterpret_cast<f32x4*>(&rawU[idx]) =
                    *reinterpret_cast<const f32x4*>(src + idx);
            }
        }
        __syncthreads();
        if (tid < 128) {   // 128 fragment-chunks for these 4 rows
            const int s   = tid >> 4;
            const int lqc = (tid >> 2) & 3;
            const int lmh = tid & 3;
            const int fi  = lmh * 1280 + s * 160 + lqc * 40;
            float u[40];
            #pragma unroll
            for (int i = 0; i < 10; ++i) {
                f32x4 t = *reinterpret_cast<const f32x4*>(&rawU[fi + i * 4]);
                u[i*4+0] = t.x; u[i*4+1] = t.y; u[i*4+2] = t.z; u[i*4+3] = t.w;
            }
            union { short8 v; unsigned short us[8]; } pk;
            #pragma unroll
            for (int j = 0; j < 8; ++j) {
                float e = u[j*5+0]*w0 + u[j*5+1]*w1 + u[j*5+2]*w2
                        + u[j*5+3]*w3 + u[j*5+4]*w4 + bb;
                pk.us[j] = f2bf(e);
            }
            const int mt = g >> 2;
            const int ll = lqc * 16 + ((g & 3) * 4 + lmh);
            Afrag[mt][s][ll] = pk.v;
        }
        __syncthreads();
    }

    // Per-lane fixed row bases (m = m0 + mt*16 + lm).
    const size_t rb0 = (size_t)(m0 +  0 + lm) * NTOP;
    const size_t rb1 = (size_t)(m0 + 16 + lm) * NTOP;
    const size_t rb2 = (size_t)(m0 + 32 + lm) * NTOP;
    const size_t rb3 = (size_t)(m0 + 48 + lm) * NTOP;

    // Load R/C dwordx4 for one 16-col n-tile, all 4 m-tiles (8 vector loads).
    auto LOADIT = [&](int nt16_, f32x4* rv_, i32x4* cv_) {
        const int nst = (nt16_ << 4) + (lq << 2);
        if (nst < NTOP) {
            rv_[0] = *reinterpret_cast<const f32x4*>(R + rb0 + nst);
            cv_[0] = *reinterpret_cast<const i32x4*>(C + rb0 + nst);
            rv_[1] = *reinterpret_cast<const f32x4*>(R + rb1 + nst);
            cv_[1] = *reinterpret_cast<const i32x4*>(C + rb1 + nst);
            rv_[2] = *reinterpret_cast<const f32x4*>(R + rb2 + nst);
            cv_[2] = *reinterpret_cast<const i32x4*>(C + rb2 + nst);
            rv_[3] = *reinterpret_cast<const f32x4*>(R + rb3 + nst);
            cv_[3] = *reinterpret_cast<const i32x4*>(C + rb3 + nst);
        } else {
            #pragma unroll
            for (int q = 0; q < 4; ++q) {
                rv_[q] = (f32x4){0.f, 0.f, 0.f, 0.f};
                cv_[q] = (i32x4){0, 0, 0, 0};
            }
        }
    };

    float lpsum = 0.f;
    const int nt0 = wave << 3;   // this wave's first 16-col n-tile (8 of 64)

    f32x4 rv[4]; i32x4 cv[4];
    LOADIT(nt0, rv, cv);

    for (int it = 0; it < 8; ++it) {
        const int nt16 = nt0 + it;

        f32x4 acc[4];
        #pragma unroll
        for (int mt = 0; mt < 4; ++mt) acc[mt] = (f32x4){0.f, 0.f, 0.f, 0.f};

        #pragma unroll
        for (int s = 0; s < 8; ++s) {
            const short8 bfr = Bf[((nt16 * 8 + s) << 6) + l];
            const short8 a0 = Afrag[0][s][l];
            const short8 a1 = Afrag[1][s][l];
            const short8 a2 = Afrag[2][s][l];
            const short8 a3 = Afrag[3][s][l];
            // swapped operands: bfr rows (n), A cols (m). One Bf load -> 4 MFMAs.
            acc[0] = __builtin_amdgcn_mfma_f32_16x16x32_bf16(bfr, a0, acc[0], 0, 0, 0);
            acc[1] = __builtin_amdgcn_mfma_f32_16x16x32_bf16(bfr, a1, acc[1], 0, 0, 0);
            acc[2] = __builtin_amdgcn_mfma_f32_16x16x32_bf16(bfr, a2, acc[2], 0, 0, 0);
            acc[3] = __builtin_amdgcn_mfma_f32_16x16x32_bf16(bfr, a3, acc[3], 0, 0, 0);
        }

        f32x4 rv2[4]; i32x4 cv2[4];

        // ---- pinned issue slot: next n-tile's R/C (after this tile's Bf loads) ----
        __builtin_amdgcn_sched_barrier(0);
        if (it < 7) LOADIT(nt16 + 1, rv2, cv2);
        __builtin_amdgcn_sched_barrier(0);

        // Consume from registers: n = nt16*16 + lq*4 + r, m = m0 + mt*16 + lm.
        #pragma unroll
        for (int mt = 0; mt < 4; ++mt) {
            #pragma unroll
            for (int r = 0; r < 4; ++r) {
                float muv = 1.f / (1.f + __expf(-acc[mt][r]));
                float d   = rv[mt][r] - muv;
                float lp  = -50.f * d * d + 1.3836465597893728f;
                if (cv[mt][r] == 1) lpsum += lp;
            }
        }

        if (it < 7) {
            rv[0] = rv2[0]; cv[0] = cv2[0];
            rv[1] = rv2[1]; cv[1] = cv2[1];
            rv[2] = rv2[2]; cv[2] = cv2[2];
            rv[3] = rv2[3]; cv[3] = cv2[3];
        }
    }

    #pragma unroll
    for (int off = 32; off > 0; off >>= 1) lpsum += __shfl_down(lpsum, off);
    if (l == 0) atomicAdd(out, lpsum);
}

extern "C" void kernel_launch(void* const* d_in, const int* in_sizes, int n_in,
                              void* d_out, int out_size, void* d_ws, size_t ws_size,
                              hipStream_t stream) {
    const float* V     = (const float*)d_in[1];
    const float* R     = (const float*)d_in[2];
    const float* nw    = (const float*)d_in[3];
    const float* U     = (const float*)d_in[4];
    const float* w5    = (const float*)d_in[5];
    const float* b1    = (const float*)d_in[6];
    const float* noise = (const float*)d_in[7];
    const int*   C     = (const int*)d_in[8];
    float* out = (float*)d_out;

    // Workspace (known-safe 532,480 B footprint):
    //   colsum: [0, 4000)      (padded to 8192)
    //   Bp    : [8192, 532480) 1024*256*2 = 524288 B
    float*          colsum = (float*)d_ws;
    unsigned short* Bp     = (unsigned short*)((char*)d_ws + 8192);

    hipMemsetAsync(colsum, 0, NTOP * sizeof(float), stream);
    hipMemsetAsync(out, 0, sizeof(float), stream);
    hipLaunchKernelGGL(k_prep, dim3(4, 125), dim3(256), 0, stream, nw, colsum);
    hipLaunchKernelGGL(k_vj, dim3(128), dim3(256), 0, stream,
                       V, noise, colsum, Bp);
    hipLaunchKernelGGL(k_main, dim3(MROWS / MBLK), dim3(512), 0, stream,
                       U, w5, b1, (const short8*)Bp, R, C, out);
}

// Round 11
// 171.406 us; speedup vs baseline: 1.3082x; 1.3082x over previous
//
#include <hip/hip_runtime.h>
#include <hip/hip_bf16.h>

typedef __attribute__((ext_vector_type(8))) short short8;
typedef __attribute__((ext_vector_type(4))) float f32x4;
typedef __attribute__((ext_vector_type(4))) int   i32x4;

#define NTOP 1000
#define KC   256
#define MROWS 40000
#define MBLK  64

static __device__ __forceinline__ unsigned short f2bf(float x) {
    union { float f; unsigned u; } v; v.f = x;
    unsigned r = (v.u + 0x7FFFu + ((v.u >> 16) & 1u)) >> 16;
    return (unsigned short)r;
}

// Kernel 1: colsum[j] += sum over an 8-row slab of nw. colsum pre-zeroed by memset.
__global__ void k_prep(const float* __restrict__ nw,
                       float* __restrict__ colsum) {
    int j  = blockIdx.x * 256 + threadIdx.x;
    int i0 = blockIdx.y * 8;
    if (j < NTOP) {
        float s = 0.f;
        int iend = min(i0 + 8, NTOP);
        for (int i = i0; i < iend; ++i) s += nw[(size_t)i * NTOP + j];
        atomicAdd(colsum + j, s);
    }
}

// Kernel 2: build B' in MFMA-fragment order:
//   B'[((nt*8 + s)*64 + lane)] (short8) = V_j[n = nt*16 + (lane&15),
//                                             k = s*32 + (lane>>4)*8 + j]
__global__ void k_vj(const float* __restrict__ V,
                     const float* __restrict__ noise,
                     const float* __restrict__ colsum,
                     unsigned short* __restrict__ Bp) {
    int t  = blockIdx.x * 256 + threadIdx.x;   // 0 .. 64*8*64-1 = 32767
    int nt = t >> 9;
    int s  = (t >> 6) & 7;
    int l  = t & 63;
    int lm = l & 15, lq = l >> 4;
    int n  = nt * 16 + lm;
    int k0 = s * 32 + lq * 8;
    union { short8 v; unsigned short us[8]; } pk;
    if (n < NTOP) {
        float cs = colsum[n];
        #pragma unroll
        for (int j = 0; j < 8; ++j) {
            int idx = n * KC + k0 + j;
            pk.us[j] = f2bf(V[idx] * cs + 0.1f * noise[idx]);
        }
    } else {
        #pragma unroll
        for (int j = 0; j < 8; ++j) pk.us[j] = 0;
    }
    reinterpret_cast<short8*>(Bp)[t] = pk.v;
}

// Kernel 3: round-8 structure (MBLK=64, 256 thr, 4 waves x 16 n-tiles, 4x B-reuse)
// + REGISTER DOUBLE-BUFFER OF Bf: next iteration's 8 fragment loads issue in a
// pinned slot BEFORE this iteration's MFMA phase. In-order vmcnt lets the MFMA
// wait retire on the old buffer while the new loads fly across MFMA+epilogue
// (~600cy > L2 latency) — removes the per-iter exposed Bf latency that r8 paid.
// (r9/r10 lesson: more waves does NOT help; the fix is per-wave pipelining.)
__global__ __launch_bounds__(256, 3) void k_main(
    const float* __restrict__ U, const float* __restrict__ w5,
    const float* __restrict__ b1, const short8* __restrict__ Bf,
    const float* __restrict__ R, const int* __restrict__ C,
    float* __restrict__ out)
{
    __shared__ short8 Afrag[4][8][64];   // [mt][s][ll] : 32 KB
    __shared__ float  rawU[5120];        // 4 U-rows    : 20 KB

    const int tid  = threadIdx.x;
    const int wave = tid >> 6;
    const int l    = tid & 63;
    const int lm = l & 15;       // output m within 16-tile (col = lane&15)
    const int lq = l >> 4;       // quad: n-subblock of 4 (row = lq*4 + r)
    const int m0 = blockIdx.x * MBLK;

    const float w0 = w5[0], w1 = w5[1], w2 = w5[2], w3 = w5[3], w4 = w5[4];
    const float bb = b1[0];

    // ---- A-build: 16 groups of 4 rows. Stage coalesced, compute from LDS. ----
    const float* ub = U + (size_t)m0 * (KC * 5);
    for (int g = 0; g < 16; ++g) {
        const float* src = ub + (size_t)g * 5120;
        #pragma unroll
        for (int j = 0; j < 5; ++j) {
            const int idx = j * 1024 + tid * 4;
            *reinterpret_cast<f32x4*>(&rawU[idx]) =
                *reinterpret_cast<const f32x4*>(src + idx);
        }
        __syncthreads();
        if (tid < 128) {   // 128 fragment-chunks for these 4 rows
            const int s   = tid >> 4;
            const int lqc = (tid >> 2) & 3;
            const int lmh = tid & 3;
            const int fi  = lmh * 1280 + s * 160 + lqc * 40;
            float u[40];
            #pragma unroll
            for (int i = 0; i < 10; ++i) {
                f32x4 t = *reinterpret_cast<const f32x4*>(&rawU[fi + i * 4]);
                u[i*4+0] = t.x; u[i*4+1] = t.y; u[i*4+2] = t.z; u[i*4+3] = t.w;
            }
            union { short8 v; unsigned short us[8]; } pk;
            #pragma unroll
            for (int j = 0; j < 8; ++j) {
                float e = u[j*5+0]*w0 + u[j*5+1]*w1 + u[j*5+2]*w2
                        + u[j*5+3]*w3 + u[j*5+4]*w4 + bb;
                pk.us[j] = f2bf(e);
            }
            const int mt = g >> 2;
            const int ll = lqc * 16 + ((g & 3) * 4 + lmh);
            Afrag[mt][s][ll] = pk.v;
        }
        __syncthreads();
    }

    // Per-lane fixed row bases (m = m0 + mt*16 + lm).
    const size_t rb0 = (size_t)(m0 +  0 + lm) * NTOP;
    const size_t rb1 = (size_t)(m0 + 16 + lm) * NTOP;
    const size_t rb2 = (size_t)(m0 + 32 + lm) * NTOP;
    const size_t rb3 = (size_t)(m0 + 48 + lm) * NTOP;

    // Load R/C dwordx4 for one 16-col n-tile, all 4 m-tiles (8 vector loads).
    auto LOADIT = [&](int nt16_, f32x4* rv_, i32x4* cv_) {
        const int nst = (nt16_ << 4) + (lq << 2);
        if (nst < NTOP) {
            rv_[0] = *reinterpret_cast<const f32x4*>(R + rb0 + nst);
            cv_[0] = *reinterpret_cast<const i32x4*>(C + rb0 + nst);
            rv_[1] = *reinterpret_cast<const f32x4*>(R + rb1 + nst);
            cv_[1] = *reinterpret_cast<const i32x4*>(C + rb1 + nst);
            rv_[2] = *reinterpret_cast<const f32x4*>(R + rb2 + nst);
            cv_[2] = *reinterpret_cast<const i32x4*>(C + rb2 + nst);
            rv_[3] = *reinterpret_cast<const f32x4*>(R + rb3 + nst);
            cv_[3] = *reinterpret_cast<const i32x4*>(C + rb3 + nst);
        } else {
            #pragma unroll
            for (int q = 0; q < 4; ++q) {
                rv_[q] = (f32x4){0.f, 0.f, 0.f, 0.f};
                cv_[q] = (i32x4){0, 0, 0, 0};
            }
        }
    };

    // Load the 8 Bf fragments of one n-tile into registers.
    auto LOADBF = [&](int nt16_, short8* b_) {
        #pragma unroll
        for (int s = 0; s < 8; ++s)
            b_[s] = Bf[((nt16_ * 8 + s) << 6) + l];
    };

    float lpsum = 0.f;
    const int nt0 = wave << 4;   // this wave's first 16-col n-tile

    short8 bfc[8], bfn[8];
    f32x4 rv[4]; i32x4 cv[4];
    LOADBF(nt0, bfc);
    LOADIT(nt0, rv, cv);

    for (int it = 0; it < 16; ++it) {
        const int nt16 = nt0 + it;

        // ---- pinned issue slot: NEXT n-tile's Bf (before this tile's MFMAs) ----
        __builtin_amdgcn_sched_barrier(0);
        if (it < 15) LOADBF(nt16 + 1, bfn);
        __builtin_amdgcn_sched_barrier(0);

        f32x4 acc[4];
        #pragma unroll
        for (int mt = 0; mt < 4; ++mt) acc[mt] = (f32x4){0.f, 0.f, 0.f, 0.f};

        #pragma unroll
        for (int s = 0; s < 8; ++s) {
            const short8 bfr = bfc[s];
            const short8 a0 = Afrag[0][s][l];
            const short8 a1 = Afrag[1][s][l];
            const short8 a2 = Afrag[2][s][l];
            const short8 a3 = Afrag[3][s][l];
            // swapped operands: bfr rows (n), A cols (m). One Bf load -> 4 MFMAs.
            acc[0] = __builtin_amdgcn_mfma_f32_16x16x32_bf16(bfr, a0, acc[0], 0, 0, 0);
            acc[1] = __builtin_amdgcn_mfma_f32_16x16x32_bf16(bfr, a1, acc[1], 0, 0, 0);
            acc[2] = __builtin_amdgcn_mfma_f32_16x16x32_bf16(bfr, a2, acc[2], 0, 0, 0);
            acc[3] = __builtin_amdgcn_mfma_f32_16x16x32_bf16(bfr, a3, acc[3], 0, 0, 0);
        }

        f32x4 rv2[4]; i32x4 cv2[4];

        // ---- pinned issue slot: next n-tile's R/C ----
        __builtin_amdgcn_sched_barrier(0);
        if (it < 15) LOADIT(nt16 + 1, rv2, cv2);
        __builtin_amdgcn_sched_barrier(0);

        // Consume from registers: n = nt16*16 + lq*4 + r, m = m0 + mt*16 + lm.
        #pragma unroll
        for (int mt = 0; mt < 4; ++mt) {
            #pragma unroll
            for (int r = 0; r < 4; ++r) {
                float muv = 1.f / (1.f + __expf(-acc[mt][r]));
                float d   = rv[mt][r] - muv;
                float lp  = -50.f * d * d + 1.3836465597893728f;
                if (cv[mt][r] == 1) lpsum += lp;
            }
        }

        if (it < 15) {
            #pragma unroll
            for (int s = 0; s < 8; ++s) bfc[s] = bfn[s];
            rv[0] = rv2[0]; cv[0] = cv2[0];
            rv[1] = rv2[1]; cv[1] = cv2[1];
            rv[2] = rv2[2]; cv[2] = cv2[2];
            rv[3] = rv2[3]; cv[3] = cv2[3];
        }
    }

    #pragma unroll
    for (int off = 32; off > 0; off >>= 1) lpsum += __shfl_down(lpsum, off);
    if (l == 0) atomicAdd(out, lpsum);
}

extern "C" void kernel_launch(void* const* d_in, const int* in_sizes, int n_in,
                              void* d_out, int out_size, void* d_ws, size_t ws_size,
                              hipStream_t stream) {
    const float* V     = (const float*)d_in[1];
    const float* R     = (const float*)d_in[2];
    const float* nw    = (const float*)d_in[3];
    const float* U     = (const float*)d_in[4];
    const float* w5    = (const float*)d_in[5];
    const float* b1    = (const float*)d_in[6];
    const float* noise = (const float*)d_in[7];
    const int*   C     = (const int*)d_in[8];
    float* out = (float*)d_out;

    // Workspace (known-safe 532,480 B footprint):
    //   colsum: [0, 4000)      (padded to 8192)
    //   Bp    : [8192, 532480) 1024*256*2 = 524288 B
    float*          colsum = (float*)d_ws;
    unsigned short* Bp     = (unsigned short*)((char*)d_ws + 8192);

    hipMemsetAsync(colsum, 0, NTOP * sizeof(float), stream);
    hipMemsetAsync(out, 0, sizeof(float), stream);
    hipLaunchKernelGGL(k_prep, dim3(4, 125), dim3(256), 0, stream, nw, colsum);
    hipLaunchKernelGGL(k_vj, dim3(128), dim3(256), 0, stream,
                       V, noise, colsum, Bp);
    hipLaunchKernelGGL(k_main, dim3(MROWS / MBLK), dim3(256), 0, stream,
                       U, w5, b1, (const short8*)Bp, R, C, out);
}